// Round 3
// baseline (130.186 us; speedup 1.0000x reference)
//
#include <hip/hip_runtime.h>

constexpr int BS = 32;
constexpr int D  = 2048;
constexpr float P = 0.5f;

constexpr int TPB = 256;            // threads per block
constexpr int NPT = 4;              // n-elements per thread (float4)
constexpr int NB  = D / (TPB*NPT);  // 2 n-blocks
constexpr int KC  = 32;             // k-chunks
constexpr int KCH = D / KC;         // 64 k rows per chunk
constexpr int NTILES = KC * NB;     // 64 weight tiles
constexpr int NBLK = NTILES * BS;   // 2048 blocks (8/CU -> fully co-resident)

// clang-native vector type: __builtin_nontemporal_load requires a pointer to
// scalar or native vector (HIP_vector_type<float,4> is rejected).
typedef float floatx4 __attribute__((ext_vector_type(4)));

__global__ __launch_bounds__(TPB) void dropconnect_kernel(
    const float* __restrict__ x,      // (BS, D)
    const float* __restrict__ weight, // (D, D)   axes (k, n)
    const float* __restrict__ bias,   // (D,)
    const float* __restrict__ u_w,    // (BS, D, D) axes (b, k, n)
    const float* __restrict__ u_b,    // (BS, D)
    float* __restrict__ out)          // (BS, D)
{
    // XCD-aware swizzle: dispatcher round-robins blockIdx.x across the 8
    // XCDs, so force all 32 batches sharing a weight tile onto ONE XCD:
    //   xcd  = f & 7   (8 XCDs)
    //   b    = (f>>3) & 31
    //   tile = xcd + 8 * (f>>8)        (8 tiles per XCD, 2 MB weight < 4 MiB L2)
    const int f    = blockIdx.x;
    const int xcd  = f & 7;
    const int b    = (f >> 3) & 31;
    const int tile = xcd + 8 * (f >> 8);   // 0..63
    const int kc   = tile & (KC - 1);      // 0..31
    const int nb   = tile >> 5;            // 0..1
    const int tid  = threadIdx.x;

    const int n0 = nb * (TPB * NPT) + tid * NPT;
    const int k0 = kc * KCH;

    // Stage the block-uniform x chunk in LDS.
    __shared__ float xs[KCH];
    if (tid < KCH) xs[tid] = x[b * D + k0 + tid];
    __syncthreads();

    const floatx4* uw4 = reinterpret_cast<const floatx4*>(u_w);
    const floatx4* w4  = reinterpret_cast<const floatx4*>(weight);
    const int DV = D / 4;

    float acc0 = 0.f, acc1 = 0.f, acc2 = 0.f, acc3 = 0.f;

    size_t iu = ((size_t)b * D + (size_t)k0) * DV + (n0 >> 2);
    size_t iw = (size_t)k0 * DV + (n0 >> 2);

#pragma unroll 4
    for (int kk = 0; kk < KCH; ++kk) {
        const float xv = xs[kk];
        // u_w is a zero-reuse 512 MiB stream: non-temporal so it doesn't
        // evict the weight tile from L2/L3.
        const floatx4 u = __builtin_nontemporal_load(&uw4[iu]);
        const floatx4 w = w4[iw];          // L2-resident after swizzle
        acc0 += (u.x <= P) ? xv * w.x : 0.f;
        acc1 += (u.y <= P) ? xv * w.y : 0.f;
        acc2 += (u.z <= P) ? xv * w.z : 0.f;
        acc3 += (u.w <= P) ? xv * w.w : 0.f;
        iu += DV;
        iw += DV;
    }

    // Fold the bias term into the kc==0 partial.
    if (kc == 0) {
        const floatx4 ub = reinterpret_cast<const floatx4*>(u_b)[(b * D + n0) >> 2];
        const floatx4 bv = reinterpret_cast<const floatx4*>(bias)[n0 >> 2];
        acc0 += (ub.x <= P) ? bv.x : 0.f;
        acc1 += (ub.y <= P) ? bv.y : 0.f;
        acc2 += (ub.z <= P) ? bv.z : 0.f;
        acc3 += (ub.w <= P) ? bv.w : 0.f;
    }

    float* o = out + (size_t)b * D + n0;
    atomicAdd(o + 0, acc0);
    atomicAdd(o + 1, acc1);
    atomicAdd(o + 2, acc2);
    atomicAdd(o + 3, acc3);
}

extern "C" void kernel_launch(void* const* d_in, const int* in_sizes, int n_in,
                              void* d_out, int out_size, void* d_ws, size_t ws_size,
                              hipStream_t stream) {
    const float* x      = (const float*)d_in[0];
    const float* weight = (const float*)d_in[1];
    const float* bias   = (const float*)d_in[2];
    const float* u_w    = (const float*)d_in[3];
    const float* u_b    = (const float*)d_in[4];
    float* out = (float*)d_out;

    // d_out is poisoned (0xAA) before timing and not re-poisoned between
    // replays — zero it ourselves every call (memset node is capture-safe).
    (void)hipMemsetAsync(out, 0, (size_t)out_size * sizeof(float), stream);

    dropconnect_kernel<<<dim3(NBLK), TPB, 0, stream>>>(x, weight, bias, u_w, u_b, out);
}

// Round 4
// 116.848 us; speedup vs baseline: 1.1142x; 1.1142x over previous
//
#include <hip/hip_runtime.h>

constexpr int BS = 32;
constexpr int D  = 2048;
constexpr float P = 0.5f;

constexpr int TPB = 256;            // threads per block
constexpr int NPT = 4;              // n-elements per thread (float4)
constexpr int NB  = D / (TPB*NPT);  // 2 n-blocks
constexpr int KC  = 32;             // k-chunks
constexpr int KCH = D / KC;         // 64 k rows per chunk
constexpr int OUTN = BS * D;        // 65536 output elements

typedef float floatx4 __attribute__((ext_vector_type(4)));

// ---------------- main kernel: partial sums, no atomics ----------------
// Template<ATOMIC>: ATOMIC=false stores partials to ws[kc][b*D+n];
// ATOMIC=true is the fallback (atomicAdd into pre-zeroed out).
template <bool ATOMIC>
__global__ __launch_bounds__(TPB) void dropconnect_kernel(
    const float* __restrict__ x,      // (BS, D)
    const float* __restrict__ weight, // (D, D)   axes (k, n)
    const float* __restrict__ bias,   // (D,)
    const float* __restrict__ u_w,    // (BS, D, D) axes (b, k, n)
    const float* __restrict__ u_b,    // (BS, D)
    float* __restrict__ dst)          // ws (KC, BS*D) or out (BS*D)
{
    const int kc  = blockIdx.x;   // k-chunk   (f%8 = kc%8 -> same-XCD tile affinity)
    const int nb  = blockIdx.y;   // n-block
    const int b   = blockIdx.z;   // batch
    const int tid = threadIdx.x;

    const int n0 = nb * (TPB * NPT) + tid * NPT;
    const int k0 = kc * KCH;

    __shared__ float xs[KCH];
    if (tid < KCH) xs[tid] = x[b * D + k0 + tid];
    __syncthreads();

    const floatx4* uw4 = reinterpret_cast<const floatx4*>(u_w);
    const floatx4* w4  = reinterpret_cast<const floatx4*>(weight);
    const int DV = D / 4;

    float acc0 = 0.f, acc1 = 0.f, acc2 = 0.f, acc3 = 0.f;

    size_t iu = ((size_t)b * D + (size_t)k0) * DV + (n0 >> 2);
    size_t iw = (size_t)k0 * DV + (n0 >> 2);

#pragma unroll 4
    for (int kk = 0; kk < KCH; ++kk) {
        const float xv = xs[kk];
        const floatx4 u = uw4[iu];
        const floatx4 w = w4[iw];
        acc0 += (u.x <= P) ? xv * w.x : 0.f;
        acc1 += (u.y <= P) ? xv * w.y : 0.f;
        acc2 += (u.z <= P) ? xv * w.z : 0.f;
        acc3 += (u.w <= P) ? xv * w.w : 0.f;
        iu += DV;
        iw += DV;
    }

    if (kc == 0) {
        const floatx4 ub = reinterpret_cast<const floatx4*>(u_b)[(b * D + n0) >> 2];
        const floatx4 bv = reinterpret_cast<const floatx4*>(bias)[n0 >> 2];
        acc0 += (ub.x <= P) ? bv.x : 0.f;
        acc1 += (ub.y <= P) ? bv.y : 0.f;
        acc2 += (ub.z <= P) ? bv.z : 0.f;
        acc3 += (ub.w <= P) ? bv.w : 0.f;
    }

    if (ATOMIC) {
        float* o = dst + (size_t)b * D + n0;
        atomicAdd(o + 0, acc0);
        atomicAdd(o + 1, acc1);
        atomicAdd(o + 2, acc2);
        atomicAdd(o + 3, acc3);
    } else {
        floatx4 v; v.x = acc0; v.y = acc1; v.z = acc2; v.w = acc3;
        // ws layout: [kc][b*D + n] — coalesced dwordx4 store, no RMW.
        reinterpret_cast<floatx4*>(dst)[((size_t)kc * OUTN + (size_t)b * D + n0) >> 2] = v;
    }
}

// ---------------- reducer: out[i] = sum_kc ws[kc][i] ----------------
__global__ __launch_bounds__(256) void reduce_kernel(
    const float* __restrict__ ws, float* __restrict__ out)
{
    const int i4 = blockIdx.x * 256 + threadIdx.x;     // float4 index
    const floatx4* w4 = reinterpret_cast<const floatx4*>(ws);
    floatx4 s = w4[i4];
#pragma unroll
    for (int kc = 1; kc < KC; ++kc) {
        const floatx4 v = w4[(size_t)kc * (OUTN / 4) + i4];
        s.x += v.x; s.y += v.y; s.z += v.z; s.w += v.w;
    }
    reinterpret_cast<floatx4*>(out)[i4] = s;
}

extern "C" void kernel_launch(void* const* d_in, const int* in_sizes, int n_in,
                              void* d_out, int out_size, void* d_ws, size_t ws_size,
                              hipStream_t stream) {
    const float* x      = (const float*)d_in[0];
    const float* weight = (const float*)d_in[1];
    const float* bias   = (const float*)d_in[2];
    const float* u_w    = (const float*)d_in[3];
    const float* u_b    = (const float*)d_in[4];
    float* out = (float*)d_out;

    const size_t ws_needed = (size_t)KC * OUTN * sizeof(float);  // 8 MiB
    dim3 grid(KC, NB, BS);

    if (ws_size >= ws_needed) {
        float* ws = (float*)d_ws;
        dropconnect_kernel<false><<<grid, TPB, 0, stream>>>(x, weight, bias, u_w, u_b, ws);
        reduce_kernel<<<OUTN / 4 / 256, 256, 0, stream>>>(ws, out);
    } else {
        // Fallback: zero + atomic accumulate (R1 path).
        (void)hipMemsetAsync(out, 0, (size_t)out_size * sizeof(float), stream);
        dropconnect_kernel<true><<<grid, TPB, 0, stream>>>(x, weight, bias, u_w, u_b, out);
    }
}